// Round 2
// baseline (853.246 us; speedup 1.0000x reference)
//
#include <hip/hip_runtime.h>
#include <math.h>

// Problem constants
#define BH 64      // (b=4) * (h=16) folded leading dim
#define NB 32      // buckets
#define BS 128     // bucket size
#define DHEAD 64   // head dim
// k/q/v flat: [bh][t=4096][64];  bucket u, pos s: off = bh*262144 + u*8192 + s*64 + d

// ---------------- threefry2x32 (JAX default PRNG), key = (0, 42) ----------------
__device__ __forceinline__ unsigned rotl32(unsigned x, int d) {
    return (x << d) | (x >> (32 - d));
}

__device__ __forceinline__ void threefry2x32(unsigned k0, unsigned k1,
                                             unsigned& x0, unsigned& x1) {
    const unsigned ks0 = k0, ks1 = k1, ks2 = k0 ^ k1 ^ 0x1BD11BDAu;
    const int r0[4] = {13, 15, 26, 6};
    const int r1[4] = {17, 29, 16, 24};
    x0 += ks0; x1 += ks1;
    #pragma unroll
    for (int i = 0; i < 4; i++) { x0 += x1; x1 = rotl32(x1, r0[i]); x1 ^= x0; }
    x0 += ks1; x1 += ks2 + 1u;
    #pragma unroll
    for (int i = 0; i < 4; i++) { x0 += x1; x1 = rotl32(x1, r1[i]); x1 ^= x0; }
    x0 += ks2; x1 += ks0 + 2u;
    #pragma unroll
    for (int i = 0; i < 4; i++) { x0 += x1; x1 = rotl32(x1, r0[i]); x1 ^= x0; }
    x0 += ks0; x1 += ks1 + 3u;
    #pragma unroll
    for (int i = 0; i < 4; i++) { x0 += x1; x1 = rotl32(x1, r1[i]); x1 ^= x0; }
    x0 += ks1; x1 += ks2 + 4u;
    #pragma unroll
    for (int i = 0; i < 4; i++) { x0 += x1; x1 = rotl32(x1, r0[i]); x1 ^= x0; }
    x0 += ks2; x1 += ks0 + 5u;
}

// jax.random.uniform bits for flat index f, *partitionable* threefry
// (jax_threefry_partitionable=True, default in modern JAX):
// counter = (hi, lo) = (f >> 32, f & 0xffffffff) = (0, f) for f < 2^32;
// 32-bit output = out0 ^ out1.
__device__ __forceinline__ float jax_uniform_part(unsigned f) {
    unsigned x0 = 0u, x1 = f;
    threefry2x32(0u, 42u, x0, x1);
    unsigned bits = x0 ^ x1;
    return __uint_as_float((bits >> 9) | 0x3F800000u) - 1.0f;
}

// ---------------- kernel 1: bucket key sums pl[bh][u][d] ----------------
__global__ void pl_kernel(const float* __restrict__ k, float* __restrict__ pl) {
    int blk = blockIdx.x;           // bh*32 + u  (2048 blocks)
    int d = threadIdx.x;            // 64 threads
    const float* kp = k + (size_t)blk * (BS * DHEAD) + d;
    float s = 0.f;
    #pragma unroll
    for (int i = 0; i < BS; i++) s += kp[i * DHEAD];
    pl[blk * DHEAD + d] = s;
}

// ---------------- kernel 2: routing (matmul + gumbel + sinkhorn + exp) ----------------
__global__ void route_kernel(const float* __restrict__ pl, const float* __restrict__ Wk,
                             float* __restrict__ Rout) {
    int bh = blockIdx.x;            // 64 blocks
    int h = bh & 15;                // bh = b*16 + h
    int tid = threadIdx.x;          // 1024 threads
    int i = tid >> 5, j = tid & 31;

    __shared__ float plS[NB * DHEAD];
    __shared__ float Rs[NB * NB];
    __shared__ float red[NB];

    for (int x = tid; x < NB * DHEAD; x += 1024) plS[x] = pl[bh * NB * DHEAD + x];
    __syncthreads();

    // R0[i,j] = sum_d pl[i,d] * W_keys[h,d,j]
    float acc = 0.f;
    #pragma unroll 8
    for (int d2 = 0; d2 < DHEAD; d2++)
        acc += plS[i * DHEAD + d2] * Wk[(h * DHEAD + d2) * NB + j];

    // gumbel noise, flat index into [4,16,32,32]
    unsigned f = (unsigned)bh * 1024u + (unsigned)i * 32u + (unsigned)j;
    float u = jax_uniform_part(f);
    float g = -logf(-logf(u + 1e-6f) + 1e-6f);
    Rs[i * 32 + j] = (acc + g) / 0.75f;
    __syncthreads();

    // 5 sinkhorn iterations: subtract row-lse (axis -1), then col-lse (axis -2)
    for (int it = 0; it < 5; it++) {
        if (tid < 32) {
            float m = -INFINITY;
            for (int c = 0; c < 32; c++) m = fmaxf(m, Rs[tid * 32 + c]);
            float s = 0.f;
            for (int c = 0; c < 32; c++) s += expf(Rs[tid * 32 + c] - m);
            red[tid] = m + logf(s);
        }
        __syncthreads();
        Rs[i * 32 + j] -= red[i];
        __syncthreads();
        if (tid < 32) {
            float m = -INFINITY;
            for (int r2 = 0; r2 < 32; r2++) m = fmaxf(m, Rs[r2 * 32 + tid]);
            float s = 0.f;
            for (int r2 = 0; r2 < 32; r2++) s += expf(Rs[r2 * 32 + tid] - m);
            red[tid] = m + logf(s);
        }
        __syncthreads();
        Rs[i * 32 + j] -= red[j];
        __syncthreads();
    }
    Rout[bh * 1024 + i * 32 + j] = expf(Rs[i * 32 + j]);
}

// ---------------- kernel 3: K' = (R + I) * K  per bh, column-parallel ----------------
__global__ void mix_kernel(const float* __restrict__ k, const float* __restrict__ R,
                           float* __restrict__ Kp) {
    __shared__ float Rs[NB * NB];
    int bh = blockIdx.x >> 3;       // 64*8 = 512 blocks
    int tile = blockIdx.x & 7;      // 1024 columns per tile (of 8192 = 128*64)
    for (int x = threadIdx.x; x < NB * NB; x += 256) Rs[x] = R[bh * 1024 + x];
    __syncthreads();
    const size_t base = (size_t)bh * (NB * BS * DHEAD);
    for (int cc = 0; cc < 4; cc++) {
        int col = tile * 1024 + cc * 256 + threadIdx.x;
        float kj[NB];
        #pragma unroll
        for (int j = 0; j < NB; j++) kj[j] = k[base + j * 8192 + col];
        #pragma unroll
        for (int i = 0; i < NB; i++) {
            float acc = kj[i];
            #pragma unroll
            for (int j = 0; j < NB; j++) acc += Rs[i * 32 + j] * kj[j];
            Kp[base + i * 8192 + col] = acc;
        }
    }
}

// ---------------- kernel 4: per-bucket attention ----------------
__global__ void __launch_bounds__(128, 1)
attn_kernel(const float* __restrict__ q, const float* __restrict__ Kp,
            const float* __restrict__ v, float* __restrict__ out) {
    __shared__ float Ks[BS][DHEAD];   // 32 KB
    __shared__ float Vs[BS][DHEAD];   // 32 KB
    int blk = blockIdx.x;             // bh*32 + u (2048 blocks)
    int tid = threadIdx.x;            // 128 threads, one Q-row each
    const size_t base = (size_t)blk * (BS * DHEAD);

    for (int x = tid; x < BS * DHEAD; x += 128) {
        ((float*)Ks)[x] = Kp[base + x];
        ((float*)Vs)[x] = v[base + x];
    }

    float qr[DHEAD];
    const float4* q4 = (const float4*)(q + base + (size_t)tid * DHEAD);
    #pragma unroll
    for (int x = 0; x < DHEAD / 4; x++) {
        float4 t = q4[x];
        qr[x * 4 + 0] = t.x; qr[x * 4 + 1] = t.y; qr[x * 4 + 2] = t.z; qr[x * 4 + 3] = t.w;
    }
    __syncthreads();

    float m = -INFINITY, l = 0.f;
    float o[DHEAD];
    #pragma unroll
    for (int d2 = 0; d2 < DHEAD; d2++) o[d2] = 0.f;

    for (int jc = 0; jc < 8; jc++) {
        float s[16];
        #pragma unroll
        for (int jj = 0; jj < 16; jj++) {
            int j = jc * 16 + jj;
            float acc = 0.f;
            #pragma unroll
            for (int d2 = 0; d2 < DHEAD; d2++) acc += qr[d2] * Ks[j][d2];
            s[jj] = acc * 0.125f;
        }
        float mc = m;
        #pragma unroll
        for (int jj = 0; jj < 16; jj++) mc = fmaxf(mc, s[jj]);
        float scale = expf(m - mc);     // first chunk: exp(-inf)=0
        l *= scale;
        #pragma unroll
        for (int d2 = 0; d2 < DHEAD; d2++) o[d2] *= scale;
        #pragma unroll
        for (int jj = 0; jj < 16; jj++) {
            int j = jc * 16 + jj;
            float p = expf(s[jj] - mc);
            l += p;
            #pragma unroll
            for (int d2 = 0; d2 < DHEAD; d2++) o[d2] += p * Vs[j][d2];
        }
        m = mc;
    }

    float inv = 1.0f / l;
    float* op = out + base + (size_t)tid * DHEAD;
    #pragma unroll
    for (int d2 = 0; d2 < DHEAD; d2++) op[d2] = o[d2] * inv;
}

extern "C" void kernel_launch(void* const* d_in, const int* in_sizes, int n_in,
                              void* d_out, int out_size, void* d_ws, size_t ws_size,
                              hipStream_t stream) {
    const float* q  = (const float*)d_in[0];
    const float* k  = (const float*)d_in[1];
    const float* v  = (const float*)d_in[2];
    const float* Wk = (const float*)d_in[3];
    // d_in[4] = W_vals — unused by the reference output path
    float* out = (float*)d_out;

    // ws layout: K' (16777216 f) | pl (131072 f) | R (65536 f)  => ~67.9 MB
    float* Kp = (float*)d_ws;
    float* pl = Kp + (size_t)16777216;
    float* R  = pl + (size_t)131072;

    pl_kernel<<<dim3(BH * NB), dim3(64), 0, stream>>>(k, pl);
    route_kernel<<<dim3(BH), dim3(1024), 0, stream>>>(pl, Wk, R);
    mix_kernel<<<dim3(BH * 8), dim3(256), 0, stream>>>(k, R, Kp);
    attn_kernel<<<dim3(BH * NB), dim3(128), 0, stream>>>(q, Kp, v, out);
}

// Round 3
// 383.977 us; speedup vs baseline: 2.2221x; 2.2221x over previous
//
#include <hip/hip_runtime.h>
#include <math.h>

// Problem constants
#define BH 64      // (b=4) * (h=16) folded leading dim
#define NB 32      // buckets
#define BS 128     // bucket size
#define DHEAD 64   // head dim

typedef __attribute__((ext_vector_type(8))) short bf16x8;
typedef __attribute__((ext_vector_type(4))) float f32x4;

#define LDK 72     // padded row (ushorts) for Kh/Kl [128][72]  (row stride 144B: 2-way-free banks)
#define LDV 76     // padded row for V [128][76]                (quads land 2-way: free)
#define LDP 136    // padded row for P [128][136]               (row stride 272B)

// ---------------- threefry2x32 (JAX partitionable PRNG), key = (0, 42) ----------------
__device__ __forceinline__ unsigned rotl32(unsigned x, int d) {
    return (x << d) | (x >> (32 - d));
}

__device__ __forceinline__ void threefry2x32(unsigned k0, unsigned k1,
                                             unsigned& x0, unsigned& x1) {
    const unsigned ks0 = k0, ks1 = k1, ks2 = k0 ^ k1 ^ 0x1BD11BDAu;
    const int r0[4] = {13, 15, 26, 6};
    const int r1[4] = {17, 29, 16, 24};
    x0 += ks0; x1 += ks1;
    #pragma unroll
    for (int i = 0; i < 4; i++) { x0 += x1; x1 = rotl32(x1, r0[i]); x1 ^= x0; }
    x0 += ks1; x1 += ks2 + 1u;
    #pragma unroll
    for (int i = 0; i < 4; i++) { x0 += x1; x1 = rotl32(x1, r1[i]); x1 ^= x0; }
    x0 += ks2; x1 += ks0 + 2u;
    #pragma unroll
    for (int i = 0; i < 4; i++) { x0 += x1; x1 = rotl32(x1, r0[i]); x1 ^= x0; }
    x0 += ks0; x1 += ks1 + 3u;
    #pragma unroll
    for (int i = 0; i < 4; i++) { x0 += x1; x1 = rotl32(x1, r1[i]); x1 ^= x0; }
    x0 += ks1; x1 += ks2 + 4u;
    #pragma unroll
    for (int i = 0; i < 4; i++) { x0 += x1; x1 = rotl32(x1, r0[i]); x1 ^= x0; }
    x0 += ks2; x1 += ks0 + 5u;
}

__device__ __forceinline__ float jax_uniform_part(unsigned f) {
    unsigned x0 = 0u, x1 = f;
    threefry2x32(0u, 42u, x0, x1);
    unsigned bits = x0 ^ x1;
    return __uint_as_float((bits >> 9) | 0x3F800000u) - 1.0f;
}

// ---------------- kernel 1: bucket key sums pl[bh][u][d] ----------------
__global__ void pl_kernel(const float* __restrict__ k, float* __restrict__ pl) {
    int blk = blockIdx.x;           // bh*32 + u  (2048 blocks)
    int d = threadIdx.x;            // 64 threads
    const float* kp = k + (size_t)blk * (BS * DHEAD) + d;
    float s = 0.f;
    #pragma unroll
    for (int i = 0; i < BS; i++) s += kp[i * DHEAD];
    pl[blk * DHEAD + d] = s;
}

// ---------------- kernel 2: routing (matmul + gumbel + sinkhorn + exp) ----------------
__global__ void route_kernel(const float* __restrict__ pl, const float* __restrict__ Wk,
                             float* __restrict__ Rout) {
    int bh = blockIdx.x;            // 64 blocks
    int h = bh & 15;                // bh = b*16 + h
    int tid = threadIdx.x;          // 1024 threads
    int i = tid >> 5, j = tid & 31;

    __shared__ float plS[NB * DHEAD];
    __shared__ float Rs[NB * NB];
    __shared__ float red[NB];

    for (int x = tid; x < NB * DHEAD; x += 1024) plS[x] = pl[bh * NB * DHEAD + x];
    __syncthreads();

    float acc = 0.f;
    #pragma unroll 8
    for (int d2 = 0; d2 < DHEAD; d2++)
        acc += plS[i * DHEAD + d2] * Wk[(h * DHEAD + d2) * NB + j];

    unsigned f = (unsigned)bh * 1024u + (unsigned)i * 32u + (unsigned)j;
    float u = jax_uniform_part(f);
    float g = -logf(-logf(u + 1e-6f) + 1e-6f);
    Rs[i * 32 + j] = (acc + g) / 0.75f;
    __syncthreads();

    for (int it = 0; it < 5; it++) {
        if (tid < 32) {
            float m = -INFINITY;
            for (int c = 0; c < 32; c++) m = fmaxf(m, Rs[tid * 32 + c]);
            float s = 0.f;
            for (int c = 0; c < 32; c++) s += expf(Rs[tid * 32 + c] - m);
            red[tid] = m + logf(s);
        }
        __syncthreads();
        Rs[i * 32 + j] -= red[i];
        __syncthreads();
        if (tid < 32) {
            float m = -INFINITY;
            for (int r2 = 0; r2 < 32; r2++) m = fmaxf(m, Rs[r2 * 32 + tid]);
            float s = 0.f;
            for (int r2 = 0; r2 < 32; r2++) s += expf(Rs[r2 * 32 + tid] - m);
            red[tid] = m + logf(s);
        }
        __syncthreads();
        Rs[i * 32 + j] -= red[j];
        __syncthreads();
    }
    Rout[bh * 1024 + i * 32 + j] = expf(Rs[i * 32 + j]);
}

// ---------------- kernel 3: K' = (R + I) * K  per bh, column-parallel ----------------
__global__ void mix_kernel(const float* __restrict__ k, const float* __restrict__ R,
                           float* __restrict__ Kp) {
    __shared__ float Rs[NB * NB];
    int bh = blockIdx.x >> 3;       // 64*8 = 512 blocks
    int tile = blockIdx.x & 7;      // 1024 columns per tile (of 8192 = 128*64)
    for (int x = threadIdx.x; x < NB * NB; x += 256) Rs[x] = R[bh * 1024 + x];
    __syncthreads();
    const size_t base = (size_t)bh * (NB * BS * DHEAD);
    for (int cc = 0; cc < 4; cc++) {
        int col = tile * 1024 + cc * 256 + threadIdx.x;
        float kj[NB];
        #pragma unroll
        for (int j = 0; j < NB; j++) kj[j] = k[base + j * 8192 + col];
        #pragma unroll
        for (int i = 0; i < NB; i++) {
            float acc = kj[i];
            #pragma unroll
            for (int j = 0; j < NB; j++) acc += Rs[i * 32 + j] * kj[j];
            Kp[base + i * 8192 + col] = acc;
        }
    }
}

// ---------------- kernel 4: per-bucket attention via MFMA ----------------
// One block (256 thr = 4 waves) per bucket. Wave w owns rows 32w..32w+31.
// S = (Q*0.125) K'^T with K' split hi/lo bf16 (3 MFMAs): score error ~1e-5.
// P, V single bf16. P LDS region aliases Kh/Kl (dead after QK) -> 56 KB LDS.
__global__ void __launch_bounds__(256)
attn_mfma_kernel(const float* __restrict__ q, const float* __restrict__ Kp,
                 const float* __restrict__ v, float* __restrict__ out) {
    __shared__ __align__(16) unsigned short smem[2 * 128 * LDK + 128 * LDV];
    unsigned short* KhS = smem;                   // [128][LDK]
    unsigned short* KlS = smem + 128 * LDK;       // [128][LDK]
    unsigned short* VbS = smem + 256 * LDK;       // [128][LDV]
    unsigned short* PbS = smem;                   // [128][LDP], aliases Kh+Kl

    const int tid = threadIdx.x;
    const int w = tid >> 6, lane = tid & 63;
    const int quad = lane >> 4, l15 = lane & 15;
    const int row0 = 32 * w;
    const size_t base = (size_t)blockIdx.x * (BS * DHEAD);

    // ---- Q A-fragments (scaled by 1/8 exactly, split hi/lo bf16) ----
    bf16x8 qh[2][2], ql[2][2];
    #pragma unroll
    for (int ti = 0; ti < 2; ti++) {
        #pragma unroll
        for (int kk = 0; kk < 2; kk++) {
            const float* qp = q + base + (size_t)(row0 + 16 * ti + l15) * DHEAD
                              + kk * 32 + quad * 8;
            float4 a = ((const float4*)qp)[0];
            float4 b = ((const float4*)qp)[1];
            float f[8] = {a.x, a.y, a.z, a.w, b.x, b.y, b.z, b.w};
            #pragma unroll
            for (int j = 0; j < 8; j++) {
                float qs = f[j] * 0.125f;                 // exact (pow2)
                unsigned bits = __float_as_uint(qs);
                unsigned short hi = (unsigned short)(bits >> 16);
                float rem = qs - __uint_as_float(bits & 0xFFFF0000u);
                unsigned short lo = (unsigned short)(__float_as_uint(rem) >> 16);
                qh[ti][kk][j] = (short)hi;
                ql[ti][kk][j] = (short)lo;
            }
        }
    }

    // ---- stage K' (split) and V (bf16) into LDS ----
    {
        int r = tid >> 1, c0 = (tid & 1) * 32;
        const float* kp = Kp + base + (size_t)r * DHEAD + c0;
        const float* vp = v  + base + (size_t)r * DHEAD + c0;
        #pragma unroll
        for (int x = 0; x < 8; x++) {
            float4 a = ((const float4*)kp)[x];
            float4 b = ((const float4*)vp)[x];
            float kf[4] = {a.x, a.y, a.z, a.w};
            float vf[4] = {b.x, b.y, b.z, b.w};
            #pragma unroll
            for (int y = 0; y < 4; y++) {
                int c = c0 + 4 * x + y;
                unsigned kb = __float_as_uint(kf[y]);
                unsigned short hi = (unsigned short)(kb >> 16);
                float rem = kf[y] - __uint_as_float(kb & 0xFFFF0000u);
                unsigned short lo = (unsigned short)(__float_as_uint(rem) >> 16);
                KhS[r * LDK + c] = hi;
                KlS[r * LDK + c] = lo;
                unsigned vb_ = __float_as_uint(vf[y]);
                VbS[r * LDV + c] = (unsigned short)((vb_ + 0x8000u) >> 16);
            }
        }
    }
    __syncthreads();

    // ---- S = Qs K'^T : 2x8 tiles of 16x16, K=64 (2 chunks), 3 split terms ----
    f32x4 acc[2][8];
    #pragma unroll
    for (int ti = 0; ti < 2; ti++)
        #pragma unroll
        for (int tc = 0; tc < 8; tc++)
            acc[ti][tc] = (f32x4){0.f, 0.f, 0.f, 0.f};

    #pragma unroll
    for (int tc = 0; tc < 8; tc++) {
        const int jrow = 16 * tc + l15;
        bf16x8 bh0 = *(const bf16x8*)&KhS[jrow * LDK + 0  + quad * 8];
        bf16x8 bh1 = *(const bf16x8*)&KhS[jrow * LDK + 32 + quad * 8];
        bf16x8 bl0 = *(const bf16x8*)&KlS[jrow * LDK + 0  + quad * 8];
        bf16x8 bl1 = *(const bf16x8*)&KlS[jrow * LDK + 32 + quad * 8];
        #pragma unroll
        for (int ti = 0; ti < 2; ti++) {
            f32x4 c = acc[ti][tc];
            c = __builtin_amdgcn_mfma_f32_16x16x32_bf16(qh[ti][0], bh0, c, 0, 0, 0);
            c = __builtin_amdgcn_mfma_f32_16x16x32_bf16(qh[ti][1], bh1, c, 0, 0, 0);
            c = __builtin_amdgcn_mfma_f32_16x16x32_bf16(ql[ti][0], bh0, c, 0, 0, 0);
            c = __builtin_amdgcn_mfma_f32_16x16x32_bf16(ql[ti][1], bh1, c, 0, 0, 0);
            c = __builtin_amdgcn_mfma_f32_16x16x32_bf16(qh[ti][0], bl0, c, 0, 0, 0);
            c = __builtin_amdgcn_mfma_f32_16x16x32_bf16(qh[ti][1], bl1, c, 0, 0, 0);
            acc[ti][tc] = c;
        }
    }

    // ---- softmax over full 128 cols (no online pass needed) ----
    // C layout: col = 16*tc + l15, row = row0 + 16*ti + quad*4 + r.
    // Row groups = 16 consecutive lanes (same quad): shuffle-xor 1,2,4,8.
    float mrow[2][4], lrow[2][4];
    #pragma unroll
    for (int ti = 0; ti < 2; ti++)
        #pragma unroll
        for (int r = 0; r < 4; r++) {
            float m = acc[ti][0][r];
            #pragma unroll
            for (int tc = 1; tc < 8; tc++) m = fmaxf(m, acc[ti][tc][r]);
            #pragma unroll
            for (int off = 1; off < 16; off <<= 1)
                m = fmaxf(m, __shfl_xor(m, off, 64));
            mrow[ti][r] = m;
        }
    #pragma unroll
    for (int ti = 0; ti < 2; ti++)
        #pragma unroll
        for (int r = 0; r < 4; r++) {
            float s = 0.f;
            #pragma unroll
            for (int tc = 0; tc < 8; tc++) {
                float p = __expf(acc[ti][tc][r] - mrow[ti][r]);
                acc[ti][tc][r] = p;
                s += p;
            }
            #pragma unroll
            for (int off = 1; off < 16; off <<= 1)
                s += __shfl_xor(s, off, 64);
            lrow[ti][r] = s;
        }

    __syncthreads();   // all waves done reading Kh/Kl before P overwrites them

    // ---- write P as bf16 into LDS (A-operand source) ----
    #pragma unroll
    for (int ti = 0; ti < 2; ti++)
        #pragma unroll
        for (int tc = 0; tc < 8; tc++)
            #pragma unroll
            for (int r = 0; r < 4; r++) {
                int prow = row0 + 16 * ti + quad * 4 + r;
                unsigned pb = __float_as_uint(acc[ti][tc][r]);
                PbS[prow * LDP + 16 * tc + l15] = (unsigned short)((pb + 0x8000u) >> 16);
            }
    __syncthreads();

    // ---- O = P V : 2x4 tiles, K=128 (4 chunks) ----
    f32x4 oacc[2][4];
    #pragma unroll
    for (int ti = 0; ti < 2; ti++)
        #pragma unroll
        for (int tc = 0; tc < 4; tc++)
            oacc[ti][tc] = (f32x4){0.f, 0.f, 0.f, 0.f};

    #pragma unroll
    for (int kc = 0; kc < 4; kc++) {
        bf16x8 aP[2];
        #pragma unroll
        for (int ti = 0; ti < 2; ti++)
            aP[ti] = *(const bf16x8*)&PbS[(row0 + 16 * ti + l15) * LDP + kc * 32 + quad * 8];
        #pragma unroll
        for (int tc = 0; tc < 4; tc++) {
            bf16x8 vb;
            #pragma unroll
            for (int j = 0; j < 8; j++)
                vb[j] = (short)VbS[(kc * 32 + quad * 8 + j) * LDV + 16 * tc + l15];
            #pragma unroll
            for (int ti = 0; ti < 2; ti++)
                oacc[ti][tc] = __builtin_amdgcn_mfma_f32_16x16x32_bf16(aP[ti], vb, oacc[ti][tc], 0, 0, 0);
        }
    }

    // ---- epilogue: normalize and store ----
    float inv[2][4];
    #pragma unroll
    for (int ti = 0; ti < 2; ti++)
        #pragma unroll
        for (int r = 0; r < 4; r++) inv[ti][r] = 1.0f / lrow[ti][r];

    #pragma unroll
    for (int ti = 0; ti < 2; ti++)
        #pragma unroll
        for (int tc = 0; tc < 4; tc++)
            #pragma unroll
            for (int r = 0; r < 4; r++) {
                int orow = row0 + 16 * ti + quad * 4 + r;
                out[base + (size_t)orow * DHEAD + 16 * tc + l15] = oacc[ti][tc][r] * inv[ti][r];
            }
}

extern "C" void kernel_launch(void* const* d_in, const int* in_sizes, int n_in,
                              void* d_out, int out_size, void* d_ws, size_t ws_size,
                              hipStream_t stream) {
    const float* q  = (const float*)d_in[0];
    const float* k  = (const float*)d_in[1];
    const float* v  = (const float*)d_in[2];
    const float* Wk = (const float*)d_in[3];
    float* out = (float*)d_out;

    // ws layout: K' (16777216 f) | pl (131072 f) | R (65536 f)
    float* Kp = (float*)d_ws;
    float* pl = Kp + (size_t)16777216;
    float* R  = pl + (size_t)131072;

    pl_kernel<<<dim3(BH * NB), dim3(64), 0, stream>>>(k, pl);
    route_kernel<<<dim3(BH), dim3(1024), 0, stream>>>(pl, Wk, R);
    mix_kernel<<<dim3(BH * 8), dim3(256), 0, stream>>>(k, R, Kp);
    attn_mfma_kernel<<<dim3(BH * NB), dim3(256), 0, stream>>>(q, Kp, v, out);
}

// Round 4
// 291.861 us; speedup vs baseline: 2.9235x; 1.3156x over previous
//
#include <hip/hip_runtime.h>
#include <math.h>

// Problem constants
#define BH 64      // (b=4) * (h=16) folded leading dim
#define NB 32      // buckets
#define BS 128     // bucket size
#define DHEAD 64   // head dim

typedef __attribute__((ext_vector_type(8))) short bf16x8;
typedef __attribute__((ext_vector_type(4))) float f32x4;

#define LDK 72     // padded row (ushorts) for Kh/Kl [128][72]
#define LDV 76     // padded row for V [128][76]
#define LDP 136    // padded row for P [128][136]

// ---------------- threefry2x32 (JAX partitionable PRNG), key = (0, 42) ----------------
__device__ __forceinline__ unsigned rotl32(unsigned x, int d) {
    return (x << d) | (x >> (32 - d));
}

__device__ __forceinline__ void threefry2x32(unsigned k0, unsigned k1,
                                             unsigned& x0, unsigned& x1) {
    const unsigned ks0 = k0, ks1 = k1, ks2 = k0 ^ k1 ^ 0x1BD11BDAu;
    const int r0[4] = {13, 15, 26, 6};
    const int r1[4] = {17, 29, 16, 24};
    x0 += ks0; x1 += ks1;
    #pragma unroll
    for (int i = 0; i < 4; i++) { x0 += x1; x1 = rotl32(x1, r0[i]); x1 ^= x0; }
    x0 += ks1; x1 += ks2 + 1u;
    #pragma unroll
    for (int i = 0; i < 4; i++) { x0 += x1; x1 = rotl32(x1, r1[i]); x1 ^= x0; }
    x0 += ks2; x1 += ks0 + 2u;
    #pragma unroll
    for (int i = 0; i < 4; i++) { x0 += x1; x1 = rotl32(x1, r0[i]); x1 ^= x0; }
    x0 += ks0; x1 += ks1 + 3u;
    #pragma unroll
    for (int i = 0; i < 4; i++) { x0 += x1; x1 = rotl32(x1, r1[i]); x1 ^= x0; }
    x0 += ks1; x1 += ks2 + 4u;
    #pragma unroll
    for (int i = 0; i < 4; i++) { x0 += x1; x1 = rotl32(x1, r0[i]); x1 ^= x0; }
    x0 += ks2; x1 += ks0 + 5u;
}

__device__ __forceinline__ float jax_uniform_part(unsigned f) {
    unsigned x0 = 0u, x1 = f;
    threefry2x32(0u, 42u, x0, x1);
    unsigned bits = x0 ^ x1;
    return __uint_as_float((bits >> 9) | 0x3F800000u) - 1.0f;
}

// ---------------- kernel 1: bucket key sums pl[bh][u][d] ----------------
// 2048 blocks (bh*32+u) x 256 threads: 4 row-groups of 32 rows, LDS reduce.
__global__ void __launch_bounds__(256)
pl_kernel(const float* __restrict__ k, float* __restrict__ pl) {
    int blk = blockIdx.x;             // bh*32 + u
    int g = threadIdx.x >> 6;         // 0..3
    int d = threadIdx.x & 63;
    const float* kp = k + (size_t)blk * 8192 + (size_t)g * 2048 + d;
    float s = 0.f;
    #pragma unroll
    for (int i = 0; i < 32; i++) s += kp[i * 64];
    __shared__ float red[4][64];
    red[g][d] = s;
    __syncthreads();
    if (threadIdx.x < 64)
        pl[blk * 64 + threadIdx.x] = (red[0][threadIdx.x] + red[1][threadIdx.x])
                                   + (red[2][threadIdx.x] + red[3][threadIdx.x]);
}

// ---------------- kernel 2: routing; writes R' = exp(sinkhorn) + I ----------------
__global__ void route_kernel(const float* __restrict__ pl, const float* __restrict__ Wk,
                             float* __restrict__ Rout) {
    int bh = blockIdx.x;            // 64 blocks
    int h = bh & 15;
    int tid = threadIdx.x;          // 1024 threads
    int i = tid >> 5, j = tid & 31; // lanes 0..31 / 32..63 of a wave = rows i, i+1

    __shared__ float plS[NB * DHEAD];
    __shared__ float T[32 * 33];
    __shared__ float colL[32];

    for (int x = tid; x < NB * DHEAD; x += 1024) plS[x] = pl[bh * NB * DHEAD + x];
    __syncthreads();

    float acc = 0.f;
    #pragma unroll 8
    for (int d2 = 0; d2 < DHEAD; d2++)
        acc += plS[i * DHEAD + d2] * Wk[(h * DHEAD + d2) * NB + j];

    unsigned f = (unsigned)bh * 1024u + (unsigned)i * 32u + (unsigned)j;
    float u = jax_uniform_part(f);
    float g = -logf(-logf(u + 1e-6f) + 1e-6f);
    float val = (acc + g) / 0.75f;

    for (int it = 0; it < 5; it++) {
        // row lse over j (32-lane shuffle butterfly)
        float m = val;
        #pragma unroll
        for (int off = 1; off < 32; off <<= 1) m = fmaxf(m, __shfl_xor(m, off, 32));
        float s = expf(val - m);
        #pragma unroll
        for (int off = 1; off < 32; off <<= 1) s += __shfl_xor(s, off, 32);
        val -= m + logf(s);

        // col lse via padded-LDS transpose
        T[i * 33 + j] = val;
        __syncthreads();
        float tv = T[j * 33 + i];       // group i now holds column i over rows j
        float m2 = tv;
        #pragma unroll
        for (int off = 1; off < 32; off <<= 1) m2 = fmaxf(m2, __shfl_xor(m2, off, 32));
        float s2 = expf(tv - m2);
        #pragma unroll
        for (int off = 1; off < 32; off <<= 1) s2 += __shfl_xor(s2, off, 32);
        if (j == 0) colL[i] = m2 + logf(s2);
        __syncthreads();
        val -= colL[j];
    }
    Rout[bh * 1024 + i * 32 + j] = expf(val) + (i == j ? 1.0f : 0.0f);
}

// ---------------- kernel 3: K' = R' * K per bh (R' includes identity) ----------------
// 2048 blocks x 256 thr. Stage 32x256 k-tile in LDS (pad 260, write/read
// conflict-optimal), thread owns 1 col, R' via uniform s_load (SGPR FMA operand).
// Phases: bulk read -> compute -> bulk write (no R/W interleave at DRAM).
__global__ void __launch_bounds__(256)
mix_kernel(const float* __restrict__ k, const float* __restrict__ Rp,
           float* __restrict__ Kp) {
    __shared__ float X[32][260];
    int bh = blockIdx.x >> 5;       // 64 bh x 32 tiles
    int tile = blockIdx.x & 31;
    const size_t kbase = (size_t)bh * 262144;
    const int col0 = tile * 256;

    {   // stage: thread loads 8 float4 from row j = tid>>3
        int j = threadIdx.x >> 3;
        int cs = (threadIdx.x & 7) * 32;
        const float4* src = (const float4*)(k + kbase + (size_t)j * 8192 + col0 + cs);
        #pragma unroll
        for (int t = 0; t < 8; t++)
            *((float4*)&X[j][cs + 4 * t]) = src[t];
    }
    __syncthreads();

    const int col = threadIdx.x;
    float xv[32];
    #pragma unroll
    for (int j = 0; j < 32; j++) xv[j] = X[j][col];

    const float* Rb = Rp + bh * 1024;   // uniform -> s_load
    float* outp = Kp + kbase + col0 + col;
    #pragma unroll 4
    for (int i = 0; i < 32; i++) {
        float acc = 0.f;
        #pragma unroll
        for (int j = 0; j < 32; j++) acc = fmaf(Rb[i * 32 + j], xv[j], acc);
        outp[(size_t)i * 8192] = acc;
    }
}

// ---------------- kernel 4: per-bucket attention via MFMA (unchanged) ----------------
__global__ void __launch_bounds__(256)
attn_mfma_kernel(const float* __restrict__ q, const float* __restrict__ Kp,
                 const float* __restrict__ v, float* __restrict__ out) {
    __shared__ __align__(16) unsigned short smem[2 * 128 * LDK + 128 * LDV];
    unsigned short* KhS = smem;                   // [128][LDK]
    unsigned short* KlS = smem + 128 * LDK;       // [128][LDK]
    unsigned short* VbS = smem + 256 * LDK;       // [128][LDV]
    unsigned short* PbS = smem;                   // [128][LDP], aliases Kh+Kl

    const int tid = threadIdx.x;
    const int w = tid >> 6, lane = tid & 63;
    const int quad = lane >> 4, l15 = lane & 15;
    const int row0 = 32 * w;
    const size_t base = (size_t)blockIdx.x * (BS * DHEAD);

    // ---- Q A-fragments (scaled by 1/8 exactly, split hi/lo bf16) ----
    bf16x8 qh[2][2], ql[2][2];
    #pragma unroll
    for (int ti = 0; ti < 2; ti++) {
        #pragma unroll
        for (int kk = 0; kk < 2; kk++) {
            const float* qp = q + base + (size_t)(row0 + 16 * ti + l15) * DHEAD
                              + kk * 32 + quad * 8;
            float4 a = ((const float4*)qp)[0];
            float4 b = ((const float4*)qp)[1];
            float f[8] = {a.x, a.y, a.z, a.w, b.x, b.y, b.z, b.w};
            #pragma unroll
            for (int j = 0; j < 8; j++) {
                float qs = f[j] * 0.125f;                 // exact (pow2)
                unsigned bits = __float_as_uint(qs);
                unsigned short hi = (unsigned short)(bits >> 16);
                float rem = qs - __uint_as_float(bits & 0xFFFF0000u);
                unsigned short lo = (unsigned short)(__float_as_uint(rem) >> 16);
                qh[ti][kk][j] = (short)hi;
                ql[ti][kk][j] = (short)lo;
            }
        }
    }

    // ---- stage K' (split) and V (bf16) into LDS ----
    {
        int r = tid >> 1, c0 = (tid & 1) * 32;
        const float* kp = Kp + base + (size_t)r * DHEAD + c0;
        const float* vp = v  + base + (size_t)r * DHEAD + c0;
        #pragma unroll
        for (int x = 0; x < 8; x++) {
            float4 a = ((const float4*)kp)[x];
            float4 b = ((const float4*)vp)[x];
            float kf[4] = {a.x, a.y, a.z, a.w};
            float vf[4] = {b.x, b.y, b.z, b.w};
            #pragma unroll
            for (int y = 0; y < 4; y++) {
                int c = c0 + 4 * x + y;
                unsigned kb = __float_as_uint(kf[y]);
                unsigned short hi = (unsigned short)(kb >> 16);
                float rem = kf[y] - __uint_as_float(kb & 0xFFFF0000u);
                unsigned short lo = (unsigned short)(__float_as_uint(rem) >> 16);
                KhS[r * LDK + c] = hi;
                KlS[r * LDK + c] = lo;
                unsigned vb_ = __float_as_uint(vf[y]);
                VbS[r * LDV + c] = (unsigned short)((vb_ + 0x8000u) >> 16);
            }
        }
    }
    __syncthreads();

    // ---- S = Qs K'^T : 2x8 tiles of 16x16, K=64 (2 chunks), 3 split terms ----
    f32x4 acc[2][8];
    #pragma unroll
    for (int ti = 0; ti < 2; ti++)
        #pragma unroll
        for (int tc = 0; tc < 8; tc++)
            acc[ti][tc] = (f32x4){0.f, 0.f, 0.f, 0.f};

    #pragma unroll
    for (int tc = 0; tc < 8; tc++) {
        const int jrow = 16 * tc + l15;
        bf16x8 bh0 = *(const bf16x8*)&KhS[jrow * LDK + 0  + quad * 8];
        bf16x8 bh1 = *(const bf16x8*)&KhS[jrow * LDK + 32 + quad * 8];
        bf16x8 bl0 = *(const bf16x8*)&KlS[jrow * LDK + 0  + quad * 8];
        bf16x8 bl1 = *(const bf16x8*)&KlS[jrow * LDK + 32 + quad * 8];
        #pragma unroll
        for (int ti = 0; ti < 2; ti++) {
            f32x4 c = acc[ti][tc];
            c = __builtin_amdgcn_mfma_f32_16x16x32_bf16(qh[ti][0], bh0, c, 0, 0, 0);
            c = __builtin_amdgcn_mfma_f32_16x16x32_bf16(qh[ti][1], bh1, c, 0, 0, 0);
            c = __builtin_amdgcn_mfma_f32_16x16x32_bf16(ql[ti][0], bh0, c, 0, 0, 0);
            c = __builtin_amdgcn_mfma_f32_16x16x32_bf16(ql[ti][1], bh1, c, 0, 0, 0);
            c = __builtin_amdgcn_mfma_f32_16x16x32_bf16(qh[ti][0], bl0, c, 0, 0, 0);
            c = __builtin_amdgcn_mfma_f32_16x16x32_bf16(qh[ti][1], bl1, c, 0, 0, 0);
            acc[ti][tc] = c;
        }
    }

    // ---- softmax over full 128 cols ----
    float mrow[2][4], lrow[2][4];
    #pragma unroll
    for (int ti = 0; ti < 2; ti++)
        #pragma unroll
        for (int r = 0; r < 4; r++) {
            float m = acc[ti][0][r];
            #pragma unroll
            for (int tc = 1; tc < 8; tc++) m = fmaxf(m, acc[ti][tc][r]);
            #pragma unroll
            for (int off = 1; off < 16; off <<= 1)
                m = fmaxf(m, __shfl_xor(m, off, 64));
            mrow[ti][r] = m;
        }
    #pragma unroll
    for (int ti = 0; ti < 2; ti++)
        #pragma unroll
        for (int r = 0; r < 4; r++) {
            float s = 0.f;
            #pragma unroll
            for (int tc = 0; tc < 8; tc++) {
                float p = __expf(acc[ti][tc][r] - mrow[ti][r]);
                acc[ti][tc][r] = p;
                s += p;
            }
            #pragma unroll
            for (int off = 1; off < 16; off <<= 1)
                s += __shfl_xor(s, off, 64);
            lrow[ti][r] = s;
        }

    __syncthreads();   // all waves done reading Kh/Kl before P overwrites them

    // ---- write P as bf16 into LDS ----
    #pragma unroll
    for (int ti = 0; ti < 2; ti++)
        #pragma unroll
        for (int tc = 0; tc < 8; tc++)
            #pragma unroll
            for (int r = 0; r < 4; r++) {
                int prow = row0 + 16 * ti + quad * 4 + r;
                unsigned pb = __float_as_uint(acc[ti][tc][r]);
                PbS[prow * LDP + 16 * tc + l15] = (unsigned short)((pb + 0x8000u) >> 16);
            }
    __syncthreads();

    // ---- O = P V : 2x4 tiles, K=128 (4 chunks) ----
    f32x4 oacc[2][4];
    #pragma unroll
    for (int ti = 0; ti < 2; ti++)
        #pragma unroll
        for (int tc = 0; tc < 4; tc++)
            oacc[ti][tc] = (f32x4){0.f, 0.f, 0.f, 0.f};

    #pragma unroll
    for (int kc = 0; kc < 4; kc++) {
        bf16x8 aP[2];
        #pragma unroll
        for (int ti = 0; ti < 2; ti++)
            aP[ti] = *(const bf16x8*)&PbS[(row0 + 16 * ti + l15) * LDP + kc * 32 + quad * 8];
        #pragma unroll
        for (int tc = 0; tc < 4; tc++) {
            bf16x8 vb;
            #pragma unroll
            for (int j = 0; j < 8; j++)
                vb[j] = (short)VbS[(kc * 32 + quad * 8 + j) * LDV + 16 * tc + l15];
            #pragma unroll
            for (int ti = 0; ti < 2; ti++)
                oacc[ti][tc] = __builtin_amdgcn_mfma_f32_16x16x32_bf16(aP[ti], vb, oacc[ti][tc], 0, 0, 0);
        }
    }

    // ---- epilogue: normalize and store ----
    float inv[2][4];
    #pragma unroll
    for (int ti = 0; ti < 2; ti++)
        #pragma unroll
        for (int r = 0; r < 4; r++) inv[ti][r] = 1.0f / lrow[ti][r];

    #pragma unroll
    for (int ti = 0; ti < 2; ti++)
        #pragma unroll
        for (int tc = 0; tc < 4; tc++)
            #pragma unroll
            for (int r = 0; r < 4; r++) {
                int orow = row0 + 16 * ti + quad * 4 + r;
                out[base + (size_t)orow * DHEAD + 16 * tc + l15] = oacc[ti][tc][r] * inv[ti][r];
            }
}

extern "C" void kernel_launch(void* const* d_in, const int* in_sizes, int n_in,
                              void* d_out, int out_size, void* d_ws, size_t ws_size,
                              hipStream_t stream) {
    const float* q  = (const float*)d_in[0];
    const float* k  = (const float*)d_in[1];
    const float* v  = (const float*)d_in[2];
    const float* Wk = (const float*)d_in[3];
    float* out = (float*)d_out;

    // ws layout: K' (16777216 f) | pl (131072 f) | R' (65536 f)
    float* Kp = (float*)d_ws;
    float* pl = Kp + (size_t)16777216;
    float* R  = pl + (size_t)131072;

    pl_kernel<<<dim3(BH * NB), dim3(256), 0, stream>>>(k, pl);
    route_kernel<<<dim3(BH), dim3(1024), 0, stream>>>(pl, Wk, R);
    mix_kernel<<<dim3(BH * NB), dim3(256), 0, stream>>>(k, R, Kp);
    attn_mfma_kernel<<<dim3(BH * NB), dim3(256), 0, stream>>>(q, Kp, v, out);
}